// Round 2
// baseline (304.386 us; speedup 1.0000x reference)
//
#include <hip/hip_runtime.h>
#include <hip/hip_bf16.h>

// out[i] = probs[X[i,0]*125000 + X[i,1]*2500 + X[i,2]*50 + X[i,3]]
//
// Traffic analysis (round 1): FETCH 492 MB vs 153 MB mandatory. The 128 MB X
// stream + 32 MB out stream evict the 25 MB table from the 4 MB per-XCD L2s,
// so ~70% of gathers miss L2 (364 MB of 64B-line re-fetches).
// Fix: (a) non-temporal loads/stores for the zero-reuse streams (X, out) so
// L2 capacity is reserved for the table; (b) 4 samples/thread to quadruple
// outstanding scattered loads per wave (VALUBusy was 1.5% — latency-starved).

typedef int v4i __attribute__((ext_vector_type(4)));

__global__ __launch_bounds__(256) void jc_gather_kernel(
    const v4i* __restrict__ X,
    const float* __restrict__ probs,
    float* __restrict__ out,
    int n)
{
    constexpr int VPT = 4;            // samples per thread
    const int tile = blockDim.x * VPT; // 1024 samples per block
    int base = blockIdx.x * tile + threadIdx.x;

    v4i x[VPT];
    int idx[VPT];

    // Phase 1: issue all X row loads (coalesced dwordx4, non-temporal).
    #pragma unroll
    for (int v = 0; v < VPT; ++v) {
        int i = base + v * 256;
        if (i < n) x[v] = __builtin_nontemporal_load(&X[i]);
    }

    // Phase 2: compute flat indices, issue all gathers (cached — table reuse).
    float val[VPT];
    #pragma unroll
    for (int v = 0; v < VPT; ++v) {
        int i = base + v * 256;
        if (i < n) {
            idx[v] = x[v].x * 125000 + x[v].y * 2500 + x[v].z * 50 + x[v].w;
            val[v] = probs[idx[v]];
        }
    }

    // Phase 3: coalesced non-temporal stores.
    #pragma unroll
    for (int v = 0; v < VPT; ++v) {
        int i = base + v * 256;
        if (i < n) __builtin_nontemporal_store(val[v], &out[i]);
    }
}

extern "C" void kernel_launch(void* const* d_in, const int* in_sizes, int n_in,
                              void* d_out, int out_size, void* d_ws, size_t ws_size,
                              hipStream_t stream) {
    const float* probs = (const float*)d_in[0];
    const v4i*   X     = (const v4i*)d_in[1];   // [N,4] int32 rows
    float* out = (float*)d_out;

    int n = out_size;  // 8,000,000
    int block = 256;
    int tile = block * 4;
    int grid = (n + tile - 1) / tile;
    jc_gather_kernel<<<grid, block, 0, stream>>>(X, probs, out, n);
}